// Round 1
// baseline (722.990 us; speedup 1.0000x reference)
//
#include <hip/hip_runtime.h>
#include <hip/hip_bf16.h>
#include <stdint.h>
#include <string.h>

// Problem constants
#define S_LEN 512
#define NBATCH 64
#define EDIM 128
#define HDIM 256
#define GDIM 1024  // 4*H

// int8 quantization for the scan GEMM (exact integer MFMA):
//   W_q = rint(W*1024) (|W|<=1/16 -> |W_q|<=64), h_q = rint(h*127),
//   gates = acc_i32 / (127*1024) + xg.
// v8: xg is pre-scaled per-gate by k_g (-log2e for i/f/o, +2log2e for g) in
// input_proj, and the dequant constant absorbs the same factor, so the scan's
// activations use exp2 directly (one mul less per transcendental).
#define WQ_SCALE 1024.0f
#define HQ_SCALE 127.0f
#define LOG2E 1.4426950408889634f
#define C_IFO (-1.1093545e-05f)  // -log2e / 130048
#define C_G (2.2187090e-05f)     // +2*log2e / 130048

typedef __attribute__((ext_vector_type(8))) short short8;   // 8 bf16 (4 VGPRs) MFMA frag
typedef __attribute__((ext_vector_type(4))) short short4v;  // 4 bf16
typedef __attribute__((ext_vector_type(4))) float float4v;  // MFMA acc
typedef __attribute__((ext_vector_type(4))) int int4v;      // 16B i8 operand / i32 acc

// Workspace layout (bytes)
#define OFF_WHH8 0u
#define SZ_WHH8 (256u * 64u * 16u)           // 256 KB: W_hh_f i8 A-frags (K=64 layout)
#define OFF_WIH (OFF_WHH8 + SZ_WHH8)
#define SZ_WIH (64u * 4u * 64u * 16u)        // 256 KB: W_ih_f bf16 frags
#define OFF_XG ((size_t)(OFF_WIH + SZ_WIH))
#define SZ_XG ((size_t)S_LEN * NBATCH * GDIM * 2)  // 67 MB: xg bf16 [t][b][1024], pre-scaled
#define OFF_HF (OFF_XG + SZ_XG)              // 64 KB: h_f final, fp32 [64][256]

__device__ __forceinline__ short f2bf(float f) {
    union { float f; unsigned u; } v;
    v.f = f;
    unsigned r = (v.u + 0x7fffu + ((v.u >> 16) & 1u)) >> 16;  // RNE
    return (short)r;
}
__device__ __forceinline__ float bf2f(short s) {
    union { unsigned u; float f; } v;
    v.u = ((unsigned)(unsigned short)s) << 16;
    return v.f;
}
__device__ __forceinline__ float sigm(float x) {
    float e = __expf(-x);                    // v_exp
    return __builtin_amdgcn_rcpf(1.0f + e);  // v_rcp
}
__device__ __forceinline__ float tanh_(float x) {
    float e = __expf(2.0f * x);              // overflow -> inf -> rcp 0 -> +1; underflow -> -1
    return 1.0f - 2.0f * __builtin_amdgcn_rcpf(e + 1.0f);
}

// ---------------------------------------------------------------------------
// Prep A: fp32 W_ih [G,128] -> bf16 MFMA A-fragments (lane(ln,q) holds
// W[tile*16+ln][c*32+q*8+j], j=0..7).
// ---------------------------------------------------------------------------
__global__ __launch_bounds__(256) void prep_frags(const float* __restrict__ src,
                                                  char* __restrict__ dst,
                                                  int K, int nchunks, int nfrags) {
    int id = blockIdx.x * blockDim.x + threadIdx.x;
    int lane = id & 63;
    int f = id >> 6;
    if (f >= nfrags) return;
    int tile = f / nchunks;
    int c = f - tile * nchunks;
    int row = tile * 16 + (lane & 15);
    int k0 = c * 32 + ((lane >> 4) * 8);
    const float* s = src + (size_t)row * K + k0;
    short8 pack;
#pragma unroll
    for (int j = 0; j < 8; ++j) pack[j] = f2bf(s[j]);
    *(short8*)(dst + ((size_t)f * 64 + lane) * 16) = pack;
}

// ---------------------------------------------------------------------------
// Prep B: fp32 W_hh [1024,256] -> int8 A-fragments for mfma_i32_16x16x64_i8,
// scaled by 1024 (|W|<=1/16 -> |W_q|<=64, no clamp needed).
// Fragment f = tile*4 + kc; lane(ln,q) byte b = W[tile*16+ln][kc*64+q*16+b]*1024.
// ---------------------------------------------------------------------------
__global__ __launch_bounds__(256) void prep_whh_i8(const float* __restrict__ src,
                                                   char* __restrict__ dst) {
    int id = blockIdx.x * blockDim.x + threadIdx.x;  // 256 frags x 64 lanes = 16384
    int lane = id & 63;
    int f = id >> 6;  // tile*4 + kc, f < 256
    int tile = f >> 2, kc = f & 3;
    int row = tile * 16 + (lane & 15);
    int k0 = kc * 64 + ((lane >> 4) * 16);
    const float* s = src + (size_t)row * HDIM + k0;
    union { char b[16]; int4v v; } u;
#pragma unroll
    for (int b = 0; b < 16; ++b)
        u.b[b] = (char)(int)rintf(s[b] * WQ_SCALE);
    *(int4v*)(dst + ((size_t)f * 64 + lane) * 16) = u.v;
}

// ---------------------------------------------------------------------------
// Input projection (transposed): xg[t][b][j] = (x[t,b,:] @ W_ih^T + b_f) * k_g
// where k_g = -log2e for gates i/f/o and +2*log2e for gate g (exp2 folding).
// A = W_ih frag, B = x^T frag -> C[m=j][n=batch].
// ---------------------------------------------------------------------------
__global__ __launch_bounds__(256) void input_proj(const int* __restrict__ seq,
                                                  const float* __restrict__ emb,
                                                  const char* __restrict__ wih_frags,
                                                  const float* __restrict__ bias,
                                                  char* __restrict__ xg) {
    __shared__ __align__(16) short lx[4][16][136];  // bf16 x-tiles, +8 pad
    int tid = threadIdx.x;
    int t0 = blockIdx.x * 4;
    int g = blockIdx.y;

    // stage x: 64 rows (4 t x 16 batch), 4 threads/row, 32 elems each
    {
        int row = tid >> 2;
        int tt = row >> 4, m = row & 15;
        int k0 = (tid & 3) * 32;
        int v = seq[(t0 + tt) * NBATCH + g * 16 + m];
        const float* src = emb + (size_t)v * EDIM + k0;
        bool zero = (v == 0);
#pragma unroll
        for (int u = 0; u < 32; u += 4) {
            float4v f = *(const float4v*)(src + u);
            short4v p;
#pragma unroll
            for (int e = 0; e < 4; ++e) p[e] = zero ? (short)0 : f2bf(f[e]);
            *(short4v*)&lx[tt][m][k0 + u] = p;
        }
    }
    __syncthreads();

    int lane = tid & 63, w = tid >> 6;
    int ln = lane & 15, q = lane >> 4;

    short8 Bx[4][4];  // x^T B-frags [t][kchunk]
#pragma unroll
    for (int tt = 0; tt < 4; ++tt)
#pragma unroll
        for (int c = 0; c < 4; ++c)
            Bx[tt][c] = *(const short8*)&lx[tt][ln][c * 32 + q * 8];

    for (int nt = 0; nt < 16; ++nt) {
        int tile = w * 16 + nt;
        // per-gate exp2 pre-scale: gate = tile>>4 (0..3 = i,f,g,o)
        float kg = ((tile >> 4) == 2) ? (2.0f * LOG2E) : (-LOG2E);
        short8 Aw[4];
#pragma unroll
        for (int c = 0; c < 4; ++c)
            Aw[c] = *(const short8*)(wih_frags + (((size_t)tile * 4 + c) * 64 + lane) * 16);
        float4v b4 = *(const float4v*)(bias + tile * 16 + q * 4);
#pragma unroll
        for (int tt = 0; tt < 4; ++tt) {
            float4v acc = b4;
#pragma unroll
            for (int c = 0; c < 4; ++c)
                acc = __builtin_amdgcn_mfma_f32_16x16x32_bf16(Aw[c], Bx[tt][c], acc, 0, 0, 0);
            short4v p;
#pragma unroll
            for (int r = 0; r < 4; ++r) p[r] = f2bf(acc[r] * kg);
            size_t off = ((size_t)(t0 + tt) * NBATCH + g * 16 + ln) * GDIM + tile * 16 + q * 4;
            *(short4v*)(xg + off * 2) = p;
        }
    }
}

// ---------------------------------------------------------------------------
// Forward LSTM scan, v8: 32 blocks x 2 batches x 8 waves (512 thr).
//   vs v7 (16 blocks x 4 batches x 16 waves):
//   - Per-CU MFMA phase unchanged (64 MFMA/SIMD/step, pipe-bound ~1300 cyc;
//     column waste 8/16 instead of 4/16 is pipe-time-free).
//   - Bh ds_read traffic halves (8 waves x 4KB), scratch traffic halves.
//   - Activation elements per CU halve (512) -> VALU tail per SIMD halves.
//   - acc zero-init via persistent zero C-operand (no per-step v_movs).
//   - exp2-folded activations (xg pre-scaled per-gate; dequant absorbs log2e).
//   Wave w owns j-tiles {g*16 + 2w+p : g=0..3, p=0..1} (32 MFMA/wave/step).
//   Element ownership: lane(q,ln): b=ln&1, rr=(ln>>1)&3, p=ln>>3,
//   j = (2w+p)*16 + q*4 + rr.
// ---------------------------------------------------------------------------
__global__ __launch_bounds__(512, 2) void lstm_scan(const char* __restrict__ whh8,
                                                    const char* __restrict__ xg,
                                                    float* __restrict__ hf_out) {
    __shared__ __align__(16) char hls[2][16][272];  // h_q i8 [buf][batch][H], +16 pad
    __shared__ __align__(16) int scr[8][256];       // per-wave scratch: [gate][64 elems]
    int tid = threadIdx.x;
    int lane = tid & 63, w = tid >> 6;  // w = 0..7
    int ln = lane & 15, q = lane >> 4;
    int bg = blockIdx.x;                // 32 batch groups of 2

    // W_hh i8 A-frags -> registers: tiles g*16 + (2w+p), 4 kc each = 32 frags (128 VGPR)
    int4v Wfr[4][2][4];
#pragma unroll
    for (int g = 0; g < 4; ++g)
#pragma unroll
        for (int p = 0; p < 2; ++p) {
            int tile = g * 16 + (w * 2 + p);
#pragma unroll
            for (int kc = 0; kc < 4; ++kc)
                Wfr[g][p][kc] = *(const int4v*)(whh8 + (((size_t)(tile * 4 + kc)) * 64 + lane) * 16);
        }

    // zero both h buffers (rows 2..15 stay zero forever -> garbage cols bounded)
    {
        int* hp = (int*)&hls[0][0][0];
        for (int i = tid; i < (2 * 16 * 272) / 4; i += 512) hp[i] = 0;
    }

    const char* hrd = &hls[0][0][0];
    char* hwr = &hls[1][0][0];
    int hoff_rd = ln * 272 + q * 16;  // B-frag: 16 contiguous bytes, +kc*64

    // element-phase ownership
    int b = ln & 1;
    int rr = (ln >> 1) & 3;
    int p = ln >> 3;
    int j = (w * 2 + p) * 16 + q * 4 + rr;
    int hoff_wr = b * 272 + j;  // 1 i8 byte

    int* swr = &scr[w][0];                                    // + g*64 + q*16 + pp*8 + ln*4 (ln<2)
    const int* srd = &scr[w][0] + (q * 16 + p * 8 + b * 4 + rr);  // + g*64

    float cst = 0.0f;

    // xg: lane's own (batch, j), pre-scaled; gate g at +g*256 elems = +512 bytes
    const char* xgp = xg + (((size_t)(bg * 2 + b) * GDIM + j) * 2);
    const size_t tstep = (size_t)NBATCH * GDIM * 2;  // 131072 B

    unsigned short xq[4];
#pragma unroll
    for (int g = 0; g < 4; ++g)
        xq[g] = *(const unsigned short*)(xgp + g * 512);

    __syncthreads();

    const int4v z4 = {0, 0, 0, 0};
    for (int t = 0; t < S_LEN; ++t) {
        // h(t-1) B-frags from read buffer: 4 x ds_read_b128
        int4v Bh[4];
#pragma unroll
        for (int kc = 0; kc < 4; ++kc)
            Bh[kc] = *(const int4v*)(hrd + hoff_rd + kc * 64);

        // stash prefetched xg (pre-scaled bf16), then issue next step's prefetch
        float xgf[4];
#pragma unroll
        for (int g = 0; g < 4; ++g) xgf[g] = bf2f((short)xq[g]);
        xgp += tstep;
        if (t != S_LEN - 1) {
#pragma unroll
            for (int g = 0; g < 4; ++g)
                xq[g] = *(const unsigned short*)(xgp + g * 512);
        }

        // 8 independent i8 MFMA chains; first kc uses the persistent zero C
        int4v a[4][2];
#pragma unroll
        for (int g = 0; g < 4; ++g)
#pragma unroll
            for (int pp = 0; pp < 2; ++pp)
                a[g][pp] = __builtin_amdgcn_mfma_i32_16x16x64_i8(Wfr[g][pp][0], Bh[0], z4, 0, 0, 0);
#pragma unroll
        for (int kc = 1; kc < 4; ++kc)
#pragma unroll
            for (int g = 0; g < 4; ++g)
#pragma unroll
                for (int pp = 0; pp < 2; ++pp)
                    a[g][pp] = __builtin_amdgcn_mfma_i32_16x16x64_i8(Wfr[g][pp][kc], Bh[kc], a[g][pp], 0, 0, 0);

        // same-wave scratch redistribution: source lanes (ln<2) publish 32 gates
        if (ln < 2) {
#pragma unroll
            for (int g = 0; g < 4; ++g)
#pragma unroll
                for (int pp = 0; pp < 2; ++pp)
                    *(int4v*)(swr + g * 64 + q * 16 + pp * 8 + ln * 4) = a[g][pp];
        }
        // gather one element's i,f,g,o; dequant (log2e-folded) + add pre-scaled xg
        float s0 = fmaf((float)srd[0], C_IFO, xgf[0]);    // i: -log2e*(raw)
        float s1 = fmaf((float)srd[64], C_IFO, xgf[1]);   // f
        float s2 = fmaf((float)srd[128], C_G, xgf[2]);    // g: +2log2e*(raw)
        float s3 = fmaf((float)srd[192], C_IFO, xgf[3]);  // o

        // exp2-based activations
        float iv = __builtin_amdgcn_rcpf(1.0f + exp2f(s0));
        float fv = __builtin_amdgcn_rcpf(1.0f + exp2f(s1));
        float gv = fmaf(-2.0f, __builtin_amdgcn_rcpf(1.0f + exp2f(s2)), 1.0f);
        float ov = __builtin_amdgcn_rcpf(1.0f + exp2f(s3));
        float cv = fmaf(fv, cst, iv * gv);
        cst = cv;
        float tc = fmaf(-2.0f, __builtin_amdgcn_rcpf(1.0f + exp2f(cv * (2.0f * LOG2E))), 1.0f);
        float hv = ov * tc;

        // h_q = rint(h*127) -> i8 byte into other buffer
        int hq = (int)rintf(hv * HQ_SCALE);
        hwr[hoff_wr] = (char)hq;

        if (t == S_LEN - 1)
            hf_out[((size_t)(bg * 2 + b)) * HDIM + j] = hv;

        const char* tr = hrd; hrd = hwr; hwr = (char*)tr;
        __syncthreads();
    }
}

// ---------------------------------------------------------------------------
// Tail: backward cell at position S-1 (h0=c0=0 => W_hh_b unused) + output proj.
// One block per batch element; thread j handles hidden unit j.
// ---------------------------------------------------------------------------
__global__ __launch_bounds__(256) void tail_kernel(const int* __restrict__ seq,
                                                   const float* __restrict__ emb,
                                                   const float* __restrict__ wih_b,
                                                   const float* __restrict__ b_b,
                                                   const float* __restrict__ wout,
                                                   const float* __restrict__ b_out,
                                                   const float* __restrict__ hf,
                                                   float* __restrict__ out) {
    __shared__ float xs[EDIM];
    __shared__ float red[4];
    int b = blockIdx.x, tid = threadIdx.x;
    if (tid < EDIM) {
        int v = seq[(S_LEN - 1) * NBATCH + b];
        xs[tid] = (v == 0) ? 0.0f : emb[(size_t)v * EDIM + tid];
    }
    __syncthreads();

    int j = tid;  // 0..255 = hidden unit
    float si = b_b[j], sg = b_b[2 * HDIM + j], so = b_b[3 * HDIM + j];
    const float* wi = wih_b + (size_t)j * EDIM;
    const float* wg = wih_b + (size_t)(2 * HDIM + j) * EDIM;
    const float* wo = wih_b + (size_t)(3 * HDIM + j) * EDIM;
#pragma unroll 8
    for (int k = 0; k < EDIM; k += 4) {
        float4v x4 = *(const float4v*)&xs[k];
        float4v a = *(const float4v*)(wi + k);
        float4v c = *(const float4v*)(wg + k);
        float4v d = *(const float4v*)(wo + k);
#pragma unroll
        for (int e = 0; e < 4; ++e) {
            si += a[e] * x4[e];
            sg += c[e] * x4[e];
            so += d[e] * x4[e];
        }
    }
    float cc = sigm(si) * tanh_(sg);   // c = i*g   (f*c0 = 0)
    float hb = sigm(so) * tanh_(cc);   // h = o*tanh(c)
    float partial = hf[(size_t)b * HDIM + j] * wout[j] + hb * wout[HDIM + j];

    float val = partial;
#pragma unroll
    for (int off = 32; off > 0; off >>= 1) val += __shfl_down(val, off, 64);
    int lane = tid & 63, wv = tid >> 6;
    if (lane == 0) red[wv] = val;
    __syncthreads();
    if (tid == 0) out[b] = sigm(red[0] + red[1] + red[2] + red[3] + b_out[0]);
}

extern "C" void kernel_launch(void* const* d_in, const int* in_sizes, int n_in,
                              void* d_out, int out_size, void* d_ws, size_t ws_size,
                              hipStream_t stream) {
    const int* seq = (const int*)d_in[0];
    const float* emb = (const float*)d_in[1];
    const float* Wih_f = (const float*)d_in[2];
    const float* Whh_f = (const float*)d_in[3];
    const float* b_f = (const float*)d_in[4];
    const float* Wih_b = (const float*)d_in[5];
    // d_in[6] = W_hh_b: provably unused (backward scan's only needed output is its
    // step 0, where h0 = 0 so the recurrent term vanishes).
    const float* b_b = (const float*)d_in[7];
    const float* Wout = (const float*)d_in[8];
    const float* b_out = (const float*)d_in[9];
    float* out = (float*)d_out;
    char* ws = (char*)d_ws;

    // 1) weight fragments: W_hh -> i8 K=64 A-frags (x1024); W_ih -> bf16 frags
    prep_whh_i8<<<dim3(64), 256, 0, stream>>>(Whh_f, ws + OFF_WHH8);
    prep_frags<<<dim3(64), 256, 0, stream>>>(Wih_f, ws + OFF_WIH, EDIM, 4, 64 * 4);
    // 2) forward input projections for all timesteps (xg bf16, per-gate exp2 pre-scale)
    input_proj<<<dim3(S_LEN / 4, 4), 256, 0, stream>>>(seq, emb, ws + OFF_WIH, b_f, ws + OFF_XG);
    // 3) sequential forward scan (32 batch groups of 2, 1 CU each, 8 waves)
    lstm_scan<<<dim3(32), 512, 0, stream>>>(ws + OFF_WHH8, ws + OFF_XG, (float*)(ws + OFF_HF));
    // 4) backward single cell + output projection
    tail_kernel<<<dim3(NBATCH), 256, 0, stream>>>(seq, emb, Wih_b, b_b, Wout, b_out,
                                                  (const float*)(ws + OFF_HF), out);
}

// Round 2
// 704.086 us; speedup vs baseline: 1.0268x; 1.0268x over previous
//
#include <hip/hip_runtime.h>
#include <hip/hip_bf16.h>
#include <stdint.h>
#include <string.h>

// Problem constants
#define S_LEN 512
#define NBATCH 64
#define EDIM 128
#define HDIM 256
#define GDIM 1024  // 4*H

// int8 quantization for the scan GEMM (exact integer MFMA):
//   W_q = rint(W*1024) (|W|<=1/16 -> |W_q|<=64), h_q = rint(h*127),
//   gates = acc_i32 / (127*1024) + xg.
// xg is pre-scaled per-gate by k_g (-log2e for i/f/o, +2log2e for g) in
// input_proj, and the dequant constant absorbs the same factor, so the scan's
// activations use exp2 directly.
#define WQ_SCALE 1024.0f
#define HQ_SCALE 127.0f
#define LOG2E 1.4426950408889634f
#define C_IFO (-1.1093545e-05f)  // -log2e / 130048
#define C_G (2.2187090e-05f)     // +2*log2e / 130048

typedef __attribute__((ext_vector_type(8))) short short8;   // 8 bf16 (4 VGPRs) MFMA frag
typedef __attribute__((ext_vector_type(4))) short short4v;  // 4 bf16
typedef __attribute__((ext_vector_type(4))) float float4v;  // MFMA acc
typedef __attribute__((ext_vector_type(4))) int int4v;      // 16B i8 operand / i32 acc

// Workspace layout (bytes)
#define OFF_WHH8 0u
#define SZ_WHH8 (256u * 64u * 16u)           // 256 KB: W_hh_f i8 A-frags (K=64 layout)
#define OFF_WIH (OFF_WHH8 + SZ_WHH8)
#define SZ_WIH (64u * 4u * 64u * 16u)        // 256 KB: W_ih_f bf16 frags
#define OFF_XG ((size_t)(OFF_WIH + SZ_WIH))
#define SZ_XG ((size_t)S_LEN * NBATCH * GDIM * 2)  // 67 MB: xg bf16 [t][b][1024], pre-scaled
#define OFF_HF (OFF_XG + SZ_XG)              // 64 KB: h_f final, fp32 [64][256]

__device__ __forceinline__ short f2bf(float f) {
    union { float f; unsigned u; } v;
    v.f = f;
    unsigned r = (v.u + 0x7fffu + ((v.u >> 16) & 1u)) >> 16;  // RNE
    return (short)r;
}
__device__ __forceinline__ float bf2f(short s) {
    union { unsigned u; float f; } v;
    v.u = ((unsigned)(unsigned short)s) << 16;
    return v.f;
}
__device__ __forceinline__ float sigm(float x) {
    float e = __expf(-x);                    // v_exp
    return __builtin_amdgcn_rcpf(1.0f + e);  // v_rcp
}
__device__ __forceinline__ float tanh_(float x) {
    float e = __expf(2.0f * x);              // overflow -> inf -> rcp 0 -> +1; underflow -> -1
    return 1.0f - 2.0f * __builtin_amdgcn_rcpf(e + 1.0f);
}

// ---------------------------------------------------------------------------
// Prep A: fp32 W_ih [G,128] -> bf16 MFMA A-fragments (lane(ln,q) holds
// W[tile*16+ln][c*32+q*8+j], j=0..7).
// ---------------------------------------------------------------------------
__global__ __launch_bounds__(256) void prep_frags(const float* __restrict__ src,
                                                  char* __restrict__ dst,
                                                  int K, int nchunks, int nfrags) {
    int id = blockIdx.x * blockDim.x + threadIdx.x;
    int lane = id & 63;
    int f = id >> 6;
    if (f >= nfrags) return;
    int tile = f / nchunks;
    int c = f - tile * nchunks;
    int row = tile * 16 + (lane & 15);
    int k0 = c * 32 + ((lane >> 4) * 8);
    const float* s = src + (size_t)row * K + k0;
    short8 pack;
#pragma unroll
    for (int j = 0; j < 8; ++j) pack[j] = f2bf(s[j]);
    *(short8*)(dst + ((size_t)f * 64 + lane) * 16) = pack;
}

// ---------------------------------------------------------------------------
// Prep B: fp32 W_hh [1024,256] -> int8 A-fragments for mfma_i32_16x16x64_i8,
// scaled by 1024 (|W|<=1/16 -> |W_q|<=64, no clamp needed).
// Fragment f = tile*4 + kc; lane(ln,q) byte b = W[tile*16+ln][kc*64+q*16+b]*1024.
// ---------------------------------------------------------------------------
__global__ __launch_bounds__(256) void prep_whh_i8(const float* __restrict__ src,
                                                   char* __restrict__ dst) {
    int id = blockIdx.x * blockDim.x + threadIdx.x;  // 256 frags x 64 lanes = 16384
    int lane = id & 63;
    int f = id >> 6;  // tile*4 + kc, f < 256
    int tile = f >> 2, kc = f & 3;
    int row = tile * 16 + (lane & 15);
    int k0 = kc * 64 + ((lane >> 4) * 16);
    const float* s = src + (size_t)row * HDIM + k0;
    union { char b[16]; int4v v; } u;
#pragma unroll
    for (int b = 0; b < 16; ++b)
        u.b[b] = (char)(int)rintf(s[b] * WQ_SCALE);
    *(int4v*)(dst + ((size_t)f * 64 + lane) * 16) = u.v;
}

// ---------------------------------------------------------------------------
// Input projection (transposed): xg[t][b][j] = (x[t,b,:] @ W_ih^T + b_f) * k_g
// where k_g = -log2e for gates i/f/o and +2*log2e for gate g (exp2 folding).
// A = W_ih frag, B = x^T frag -> C[m=j][n=batch].
// ---------------------------------------------------------------------------
__global__ __launch_bounds__(256) void input_proj(const int* __restrict__ seq,
                                                  const float* __restrict__ emb,
                                                  const char* __restrict__ wih_frags,
                                                  const float* __restrict__ bias,
                                                  char* __restrict__ xg) {
    __shared__ __align__(16) short lx[4][16][136];  // bf16 x-tiles, +8 pad
    int tid = threadIdx.x;
    int t0 = blockIdx.x * 4;
    int g = blockIdx.y;

    // stage x: 64 rows (4 t x 16 batch), 4 threads/row, 32 elems each
    {
        int row = tid >> 2;
        int tt = row >> 4, m = row & 15;
        int k0 = (tid & 3) * 32;
        int v = seq[(t0 + tt) * NBATCH + g * 16 + m];
        const float* src = emb + (size_t)v * EDIM + k0;
        bool zero = (v == 0);
#pragma unroll
        for (int u = 0; u < 32; u += 4) {
            float4v f = *(const float4v*)(src + u);
            short4v p;
#pragma unroll
            for (int e = 0; e < 4; ++e) p[e] = zero ? (short)0 : f2bf(f[e]);
            *(short4v*)&lx[tt][m][k0 + u] = p;
        }
    }
    __syncthreads();

    int lane = tid & 63, w = tid >> 6;
    int ln = lane & 15, q = lane >> 4;

    short8 Bx[4][4];  // x^T B-frags [t][kchunk]
#pragma unroll
    for (int tt = 0; tt < 4; ++tt)
#pragma unroll
        for (int c = 0; c < 4; ++c)
            Bx[tt][c] = *(const short8*)&lx[tt][ln][c * 32 + q * 8];

    for (int nt = 0; nt < 16; ++nt) {
        int tile = w * 16 + nt;
        // per-gate exp2 pre-scale: gate = tile>>4 (0..3 = i,f,g,o)
        float kg = ((tile >> 4) == 2) ? (2.0f * LOG2E) : (-LOG2E);
        short8 Aw[4];
#pragma unroll
        for (int c = 0; c < 4; ++c)
            Aw[c] = *(const short8*)(wih_frags + (((size_t)tile * 4 + c) * 64 + lane) * 16);
        float4v b4 = *(const float4v*)(bias + tile * 16 + q * 4);
#pragma unroll
        for (int tt = 0; tt < 4; ++tt) {
            float4v acc = b4;
#pragma unroll
            for (int c = 0; c < 4; ++c)
                acc = __builtin_amdgcn_mfma_f32_16x16x32_bf16(Aw[c], Bx[tt][c], acc, 0, 0, 0);
            short4v p;
#pragma unroll
            for (int r = 0; r < 4; ++r) p[r] = f2bf(acc[r] * kg);
            size_t off = ((size_t)(t0 + tt) * NBATCH + g * 16 + ln) * GDIM + tile * 16 + q * 4;
            *(short4v*)(xg + off * 2) = p;
        }
    }
}

// ---------------------------------------------------------------------------
// Forward LSTM scan, v9: 16 blocks x 4 batches x 16 waves (1024 thr).
//   Back to v7's wave count (4 waves/SIMD: latency hiding was worth more than
//   v8's VALU savings — v8 post-mortem: residual DS/barrier stalls doubled).
//   Deltas vs v7:
//   - z4 zero-C MFMA init (no per-step acc zeroing)           [from v8]
//   - exp2-folded activations (xg pre-scaled per-gate)        [from v8]
//   - conflict-free scratch: scr[w][g*64+q*16+b*4+rr] -> all DS accesses
//     <=2-way (2-way is free per m136). v7's stride-20 was 4-8-way.
//   - h tile: [buf][4][320] with BROADCAST Bh reads: lanes ln>=4 read
//     duplicate of ln&3 (broadcasts free; C-cols 4..15 unused). 320-pad
//     (80 ints == 16 mod 32) gives exactly 2-way on the 16 unique addrs.
//   Wave w owns j-tile w for all 4 gates: tiles {g*16+w}, 16 MFMA/wave/step.
//   Element ownership (lane-dense): lane(q,ln): b=ln&3, rr=ln>>2,
//   j = w*16 + q*4 + rr.
// ---------------------------------------------------------------------------
#define HPAD 320
__global__ __launch_bounds__(1024, 4) void lstm_scan(const char* __restrict__ whh8,
                                                     const char* __restrict__ xg,
                                                     float* __restrict__ hf_out) {
    __shared__ __align__(16) char hls[2][4][HPAD];  // h_q i8 [buf][batch][H], pad to 320
    __shared__ __align__(16) int scr[16][256];      // per-wave scratch [g][q][b][rr]
    int tid = threadIdx.x;
    int lane = tid & 63, w = tid >> 6;  // w = 0..15: hidden j-tile
    int ln = lane & 15, q = lane >> 4;
    int bg = blockIdx.x;                // 16 batch groups of 4

    // W_hh i8 A-frags -> registers: tiles g*16+w, 4 kc each = 16 frags (64 regs)
    int4v Wfr[4][4];
#pragma unroll
    for (int g = 0; g < 4; ++g) {
        int tile = g * 16 + w;
#pragma unroll
        for (int kc = 0; kc < 4; ++kc)
            Wfr[g][kc] = *(const int4v*)(whh8 + (((size_t)(tile * 4 + kc)) * 64 + lane) * 16);
    }

    // zero both h buffers
    {
        int* hp = (int*)&hls[0][0][0];
        for (int i = tid; i < (2 * 4 * HPAD) / 4; i += 1024) hp[i] = 0;
    }

    const char* hrd = &hls[0][0][0];
    char* hwr = &hls[1][0][0];
    // broadcast read: lanes ln>=4 duplicate column ln&3 (free; cols 4..15 unused)
    int hoff_rd = (ln & 3) * HPAD + q * 16;  // B-frag: 16 contiguous bytes, +kc*64

    // element-phase ownership (lane-dense): all 64 lanes own one element
    int b = ln & 3;
    int rr = ln >> 2;
    int j = w * 16 + q * 4 + rr;
    int hoff_wr = b * HPAD + j;  // 1 i8 byte

    int* swr = &scr[w][q * 16 + ln * 4];           // writer (ln<4): +g*64, int4v
    const int* srd = &scr[w][q * 16 + b * 4 + rr]; // reader: +g*64, b32

    float cst = 0.0f;

    // xg: lane's own (batch, j), pre-scaled; gate g at +g*256 elems = +512 bytes
    const char* xgp = xg + (((size_t)(bg * 4 + b) * GDIM + j) * 2);
    const size_t tstep = (size_t)NBATCH * GDIM * 2;  // 131072 B

    unsigned short xq[4];
#pragma unroll
    for (int g = 0; g < 4; ++g)
        xq[g] = *(const unsigned short*)(xgp + g * 512);

    __syncthreads();

    const int4v z4 = {0, 0, 0, 0};
    for (int t = 0; t < S_LEN; ++t) {
        // h(t-1) B-frags from read buffer: 4 x ds_read_b128 (2-way max, free)
        int4v Bh[4];
#pragma unroll
        for (int kc = 0; kc < 4; ++kc)
            Bh[kc] = *(const int4v*)(hrd + hoff_rd + kc * 64);

        // stash prefetched xg (pre-scaled bf16), then issue next step's prefetch
        float xgf[4];
#pragma unroll
        for (int g = 0; g < 4; ++g) xgf[g] = bf2f((short)xq[g]);
        xgp += tstep;
        if (t != S_LEN - 1) {
#pragma unroll
            for (int g = 0; g < 4; ++g)
                xq[g] = *(const unsigned short*)(xgp + g * 512);
        }

        // 4 independent i8 MFMA chains, chunk-major, zero C-operand on kc=0
        int4v a[4];
#pragma unroll
        for (int g = 0; g < 4; ++g)
            a[g] = __builtin_amdgcn_mfma_i32_16x16x64_i8(Wfr[g][0], Bh[0], z4, 0, 0, 0);
#pragma unroll
        for (int kc = 1; kc < 4; ++kc)
#pragma unroll
            for (int g = 0; g < 4; ++g)
                a[g] = __builtin_amdgcn_mfma_i32_16x16x64_i8(Wfr[g][kc], Bh[kc], a[g], 0, 0, 0);

        // same-wave scratch redistribution (conflict-free layout [g][q][b][rr])
        if (ln < 4) {
#pragma unroll
            for (int g = 0; g < 4; ++g)
                *(int4v*)(swr + g * 64) = a[g];
        }
        // gather one element's i,f,g,o; dequant (log2e-folded) + add pre-scaled xg
        float s0 = fmaf((float)srd[0], C_IFO, xgf[0]);    // i
        float s1 = fmaf((float)srd[64], C_IFO, xgf[1]);   // f
        float s2 = fmaf((float)srd[128], C_G, xgf[2]);    // g
        float s3 = fmaf((float)srd[192], C_IFO, xgf[3]);  // o

        // exp2-based activations
        float iv = __builtin_amdgcn_rcpf(1.0f + exp2f(s0));
        float fv = __builtin_amdgcn_rcpf(1.0f + exp2f(s1));
        float gv = fmaf(-2.0f, __builtin_amdgcn_rcpf(1.0f + exp2f(s2)), 1.0f);
        float ov = __builtin_amdgcn_rcpf(1.0f + exp2f(s3));
        float cv = fmaf(fv, cst, iv * gv);
        cst = cv;
        float tc = fmaf(-2.0f, __builtin_amdgcn_rcpf(1.0f + exp2f(cv * (2.0f * LOG2E))), 1.0f);
        float hv = ov * tc;

        // h_q = rint(h*127) -> i8 byte into other buffer
        int hq = (int)rintf(hv * HQ_SCALE);
        hwr[hoff_wr] = (char)hq;

        if (t == S_LEN - 1)
            hf_out[((size_t)(bg * 4 + b)) * HDIM + j] = hv;

        const char* tr = hrd; hrd = hwr; hwr = (char*)tr;
        __syncthreads();
    }
}

// ---------------------------------------------------------------------------
// Tail: backward cell at position S-1 (h0=c0=0 => W_hh_b unused) + output proj.
// One block per batch element; thread j handles hidden unit j.
// ---------------------------------------------------------------------------
__global__ __launch_bounds__(256) void tail_kernel(const int* __restrict__ seq,
                                                   const float* __restrict__ emb,
                                                   const float* __restrict__ wih_b,
                                                   const float* __restrict__ b_b,
                                                   const float* __restrict__ wout,
                                                   const float* __restrict__ b_out,
                                                   const float* __restrict__ hf,
                                                   float* __restrict__ out) {
    __shared__ float xs[EDIM];
    __shared__ float red[4];
    int b = blockIdx.x, tid = threadIdx.x;
    if (tid < EDIM) {
        int v = seq[(S_LEN - 1) * NBATCH + b];
        xs[tid] = (v == 0) ? 0.0f : emb[(size_t)v * EDIM + tid];
    }
    __syncthreads();

    int j = tid;  // 0..255 = hidden unit
    float si = b_b[j], sg = b_b[2 * HDIM + j], so = b_b[3 * HDIM + j];
    const float* wi = wih_b + (size_t)j * EDIM;
    const float* wg = wih_b + (size_t)(2 * HDIM + j) * EDIM;
    const float* wo = wih_b + (size_t)(3 * HDIM + j) * EDIM;
#pragma unroll 8
    for (int k = 0; k < EDIM; k += 4) {
        float4v x4 = *(const float4v*)&xs[k];
        float4v a = *(const float4v*)(wi + k);
        float4v c = *(const float4v*)(wg + k);
        float4v d = *(const float4v*)(wo + k);
#pragma unroll
        for (int e = 0; e < 4; ++e) {
            si += a[e] * x4[e];
            sg += c[e] * x4[e];
            so += d[e] * x4[e];
        }
    }
    float cc = sigm(si) * tanh_(sg);   // c = i*g   (f*c0 = 0)
    float hb = sigm(so) * tanh_(cc);   // h = o*tanh(c)
    float partial = hf[(size_t)b * HDIM + j] * wout[j] + hb * wout[HDIM + j];

    float val = partial;
#pragma unroll
    for (int off = 32; off > 0; off >>= 1) val += __shfl_down(val, off, 64);
    int lane = tid & 63, wv = tid >> 6;
    if (lane == 0) red[wv] = val;
    __syncthreads();
    if (tid == 0) out[b] = sigm(red[0] + red[1] + red[2] + red[3] + b_out[0]);
}

extern "C" void kernel_launch(void* const* d_in, const int* in_sizes, int n_in,
                              void* d_out, int out_size, void* d_ws, size_t ws_size,
                              hipStream_t stream) {
    const int* seq = (const int*)d_in[0];
    const float* emb = (const float*)d_in[1];
    const float* Wih_f = (const float*)d_in[2];
    const float* Whh_f = (const float*)d_in[3];
    const float* b_f = (const float*)d_in[4];
    const float* Wih_b = (const float*)d_in[5];
    // d_in[6] = W_hh_b: provably unused (backward scan's only needed output is its
    // step 0, where h0 = 0 so the recurrent term vanishes).
    const float* b_b = (const float*)d_in[7];
    const float* Wout = (const float*)d_in[8];
    const float* b_out = (const float*)d_in[9];
    float* out = (float*)d_out;
    char* ws = (char*)d_ws;

    // 1) weight fragments: W_hh -> i8 K=64 A-frags (x1024); W_ih -> bf16 frags
    prep_whh_i8<<<dim3(64), 256, 0, stream>>>(Whh_f, ws + OFF_WHH8);
    prep_frags<<<dim3(64), 256, 0, stream>>>(Wih_f, ws + OFF_WIH, EDIM, 4, 64 * 4);
    // 2) forward input projections for all timesteps (xg bf16, per-gate exp2 pre-scale)
    input_proj<<<dim3(S_LEN / 4, 4), 256, 0, stream>>>(seq, emb, ws + OFF_WIH, b_f, ws + OFF_XG);
    // 3) sequential forward scan (16 batch groups of 4, 1 CU each, 16 waves)
    lstm_scan<<<dim3(16), 1024, 0, stream>>>(ws + OFF_WHH8, ws + OFF_XG, (float*)(ws + OFF_HF));
    // 4) backward single cell + output projection
    tail_kernel<<<dim3(NBATCH), 256, 0, stream>>>(seq, emb, Wih_b, b_b, Wout, b_out,
                                                  (const float*)(ws + OFF_HF), out);
}